// Round 2
// baseline (193.397 us; speedup 1.0000x reference)
//
#include <hip/hip_runtime.h>
#include <hip/hip_bf16.h>

typedef __bf16 bf16x8 __attribute__((ext_vector_type(8)));
typedef float  f32x16 __attribute__((ext_vector_type(16)));

static constexpr int Bz = 2, Nn = 4096, Ee = 4, Dd = 64, ADim = 32;
static constexpr int Mm = Nn * Ee;  // 16384 reduction dim

__device__ __forceinline__ bf16x8 cvt8(float4 a, float4 b) {
  bf16x8 r;
  r[0] = (__bf16)a.x; r[1] = (__bf16)a.y; r[2] = (__bf16)a.z; r[3] = (__bf16)a.w;
  r[4] = (__bf16)b.x; r[5] = (__bf16)b.y; r[6] = (__bf16)b.z; r[7] = (__bf16)b.w;
  return r;
}
__device__ __forceinline__ f32x16 zero16() {
  f32x16 z;
#pragma unroll
  for (int i = 0; i < 16; ++i) z[i] = 0.f;
  return z;
}
__device__ __forceinline__ f32x16 mm(bf16x8 a, bf16x8 b, f32x16 c) {
  return __builtin_amdgcn_mfma_f32_32x32x16_bf16(a, b, c, 0, 0, 0);
}
__device__ __forceinline__ float sigm(float x) { return 1.f / (1.f + __expf(-x)); }
__device__ __forceinline__ float tanh_fast(float x) {
  float e = __expf(2.f * x);
  return 1.f - 2.f / (e + 1.f);
}

// -------- Kernel 1: Bt[b][d][e*N+n] = sum_d' W_in[e][d][d'] * prop[b][n][d'] + b_in[e][d], bf16
__global__ __launch_bounds__(256) void k_build_bt(
    const float* __restrict__ prop, const float* __restrict__ Win,
    const float* __restrict__ bin, __bf16* __restrict__ Bt) {
  const int nchunk = blockIdx.x;          // 0..63  (64 n per block)
  const int e = blockIdx.y, b = blockIdx.z;
  const int tid = threadIdx.x;
  const int w = tid >> 6, l = tid & 63;
  const int r31 = l & 31, h = l >> 5;
  const int oh = w & 1, ns = w >> 1;
  const int o_row = oh * 32 + r31;                       // A-frag row (output dim)
  const int n_col = nchunk * 64 + ns * 32 + r31;         // B-frag col (node)
  const float* wbase = Win + ((size_t)e * 64 + o_row) * 64 + 8 * h;
  const float* pbase = prop + ((size_t)b * Nn + n_col) * 64 + 8 * h;
  f32x16 acc = zero16();
#pragma unroll
  for (int ks = 0; ks < 4; ++ks) {
    float4 w0 = *reinterpret_cast<const float4*>(wbase + 16 * ks);
    float4 w1 = *reinterpret_cast<const float4*>(wbase + 16 * ks + 4);
    float4 p0 = *reinterpret_cast<const float4*>(pbase + 16 * ks);
    float4 p1 = *reinterpret_cast<const float4*>(pbase + 16 * ks + 4);
    acc = mm(cvt8(w0, w1), cvt8(p0, p1), acc);
  }
#pragma unroll
  for (int reg = 0; reg < 16; ++reg) {
    int orow = oh * 32 + (reg & 3) + 8 * (reg >> 2) + 4 * h;
    float v = acc[reg] + bin[e * 64 + orow];
    Bt[((size_t)b * 64 + orow) * Mm + (size_t)e * Nn + n_col] = (__bf16)v;
  }
}

// -------- Kernel 2: a_in[b][n][d] = sum_m A[b][n][m] * Bt[b][d][m]   (bf16 MFMA, f32 acc)
__global__ __launch_bounds__(512) void k_big_gemm(
    const float* __restrict__ A, const __bf16* __restrict__ Bt,
    float* __restrict__ a_in) {
  __shared__ float red[8][32][64];  // 64 KB
  const int bid = blockIdx.x;
  const int b = bid >> 7;            // 128 row-tiles per batch
  const int n0 = (bid & 127) * 32;
  const int tid = threadIdx.x;
  const int w = tid >> 6, l = tid & 63;
  const int r31 = l & 31, h = l >> 5;
  const size_t kstart = (size_t)w * 2048;  // K split 8 ways across waves

  const float* ap = A + ((size_t)b * Nn + (n0 + r31)) * Mm + kstart + 8 * h;
  const __bf16* bp0 = Bt + ((size_t)b * 64 + r31) * Mm + kstart + 8 * h;
  const __bf16* bp1 = bp0 + (size_t)32 * Mm;

  f32x16 acc0 = zero16(), acc1 = zero16();
#pragma unroll 4
  for (int s = 0; s < 128; ++s) {
    float4 a0 = *reinterpret_cast<const float4*>(ap);
    float4 a1 = *reinterpret_cast<const float4*>(ap + 4);
    bf16x8 fb0 = *reinterpret_cast<const bf16x8*>(bp0);
    bf16x8 fb1 = *reinterpret_cast<const bf16x8*>(bp1);
    bf16x8 fa = cvt8(a0, a1);
    acc0 = mm(fa, fb0, acc0);
    acc1 = mm(fa, fb1, acc1);
    ap += 16; bp0 += 16; bp1 += 16;
  }
#pragma unroll
  for (int reg = 0; reg < 16; ++reg) {
    int row = (reg & 3) + 8 * (reg >> 2) + 4 * h;
    red[w][row][r31] = acc0[reg];
    red[w][row][32 + r31] = acc1[reg];
  }
  __syncthreads();
  // reduce 8 wave-partials; 512 threads x 4 floats = 2048 outputs
  const int idx = tid * 4;
  const int row = idx >> 6, c4 = idx & 63;
  float s0 = 0.f, s1 = 0.f, s2 = 0.f, s3 = 0.f;
#pragma unroll
  for (int ww = 0; ww < 8; ++ww) {
    float4 v = *reinterpret_cast<const float4*>(&red[ww][row][c4]);
    s0 += v.x; s1 += v.y; s2 += v.z; s3 += v.w;
  }
  float4 o; o.x = s0; o.y = s1; o.z = s2; o.w = s3;
  *reinterpret_cast<float4*>(a_in + ((size_t)(b * Nn + n0 + row)) * 64 + c4) = o;
}

// -------- Kernel 3: GRU gate update + output head, 1 wave per 32 rows
__global__ __launch_bounds__(64) void k_gru(
    const float* __restrict__ a_in, const float* __restrict__ prop,
    const float* __restrict__ annot,
    const float* __restrict__ Wr, const float* __restrict__ br,
    const float* __restrict__ Wz, const float* __restrict__ bz,
    const float* __restrict__ Wh, const float* __restrict__ bh,
    const float* __restrict__ Wo1, const float* __restrict__ bo1,
    const float* __restrict__ Wo2, const float* __restrict__ bo2,
    float* __restrict__ out) {
  __shared__ float plds[32][68];
  __shared__ float tlds[32][68];
  const int R0 = blockIdx.x * 32;  // flat row = b*N + n
  const int l = threadIdx.x;
  const int r31 = l & 31, h = l >> 5;

  // ---- load A-frags for X1 = [a_in | prop]; stash prop f32 tile into LDS
  bf16x8 xa[4], xp[4], xan[2];
  {
    const float* ab = a_in + (size_t)(R0 + r31) * 64 + 8 * h;
    const float* pb = prop + (size_t)(R0 + r31) * 64 + 8 * h;
#pragma unroll
    for (int ks = 0; ks < 4; ++ks) {
      float4 a0 = *reinterpret_cast<const float4*>(ab + 16 * ks);
      float4 a1 = *reinterpret_cast<const float4*>(ab + 16 * ks + 4);
      xa[ks] = cvt8(a0, a1);
      float4 p0 = *reinterpret_cast<const float4*>(pb + 16 * ks);
      float4 p1 = *reinterpret_cast<const float4*>(pb + 16 * ks + 4);
      xp[ks] = cvt8(p0, p1);
      *reinterpret_cast<float4*>(&plds[r31][16 * ks + 8 * h]) = p0;
      *reinterpret_cast<float4*>(&plds[r31][16 * ks + 8 * h + 4]) = p1;
    }
    const float* anb = annot + (size_t)(R0 + r31) * ADim + 8 * h;
#pragma unroll
    for (int ks = 0; ks < 2; ++ks) {
      float4 a0 = *reinterpret_cast<const float4*>(anb + 16 * ks);
      float4 a1 = *reinterpret_cast<const float4*>(anb + 16 * ks + 4);
      xan[ks] = cvt8(a0, a1);
    }
  }
  __syncthreads();

  // weight fragment loader: B-operand = W^T, W row-major [64][L]
#define LDW(W, L, oh, ks) ({                                                 \
    const float* wb_ = (W) + (size_t)(32 * (oh) + r31) * (L) + 16 * (ks) + 8 * h; \
    float4 w0_ = *reinterpret_cast<const float4*>(wb_);                      \
    float4 w1_ = *reinterpret_cast<const float4*>(wb_ + 4);                  \
    cvt8(w0_, w1_); })

  // ---- gates r, z : X1 @ {Wr,Wz}^T
  f32x16 aR[2] = {zero16(), zero16()}, aZ[2] = {zero16(), zero16()};
#pragma unroll
  for (int ks = 0; ks < 8; ++ks) {
    bf16x8 af = (ks < 4) ? xa[ks] : xp[ks - 4];
#pragma unroll
    for (int oh = 0; oh < 2; ++oh) {
      aR[oh] = mm(af, LDW(Wr, 128, oh, ks), aR[oh]);
      aZ[oh] = mm(af, LDW(Wz, 128, oh, ks), aZ[oh]);
    }
  }
  const float br_[2] = {br[r31], br[32 + r31]};
  const float bz_[2] = {bz[r31], bz[32 + r31]};
  float propv[2][16], zv[2][16];
#pragma unroll
  for (int oh = 0; oh < 2; ++oh) {
#pragma unroll
    for (int reg = 0; reg < 16; ++reg) {
      int row = (reg & 3) + 8 * (reg >> 2) + 4 * h;
      int o = 32 * oh + r31;
      propv[oh][reg] = plds[row][o];
      float rv = sigm(aR[oh][reg] + br_[oh]);
      zv[oh][reg] = sigm(aZ[oh][reg] + bz_[oh]);
      tlds[row][o] = rv * propv[oh][reg];  // r * prop, C/D layout -> LDS
    }
  }
  __syncthreads();
  bf16x8 xr[4];
#pragma unroll
  for (int ks = 0; ks < 4; ++ks) {
    float4 t0 = *reinterpret_cast<const float4*>(&tlds[r31][16 * ks + 8 * h]);
    float4 t1 = *reinterpret_cast<const float4*>(&tlds[r31][16 * ks + 8 * h + 4]);
    xr[ks] = cvt8(t0, t1);
  }
  // ---- candidate h_hat : [a_in | r*prop] @ Wh^T
  f32x16 aH[2] = {zero16(), zero16()};
#pragma unroll
  for (int ks = 0; ks < 8; ++ks) {
    bf16x8 af = (ks < 4) ? xa[ks] : xr[ks - 4];
#pragma unroll
    for (int oh = 0; oh < 2; ++oh) aH[oh] = mm(af, LDW(Wh, 128, oh, ks), aH[oh]);
  }
  __syncthreads();  // xr reads done before tlds overwrite
  const float bh_[2] = {bh[r31], bh[32 + r31]};
#pragma unroll
  for (int oh = 0; oh < 2; ++oh) {
#pragma unroll
    for (int reg = 0; reg < 16; ++reg) {
      int row = (reg & 3) + 8 * (reg >> 2) + 4 * h;
      int o = 32 * oh + r31;
      float hh = tanh_fast(aH[oh][reg] + bh_[oh]);
      float z = zv[oh][reg];
      tlds[row][o] = (1.f - z) * propv[oh][reg] + z * hh;  // new_state
    }
  }
  __syncthreads();
  bf16x8 xn[4];
#pragma unroll
  for (int ks = 0; ks < 4; ++ks) {
    float4 t0 = *reinterpret_cast<const float4*>(&tlds[r31][16 * ks + 8 * h]);
    float4 t1 = *reinterpret_cast<const float4*>(&tlds[r31][16 * ks + 8 * h + 4]);
    xn[ks] = cvt8(t0, t1);
  }
  // ---- output head: h = tanh([new | annot] @ Wo1^T + bo1); out = h @ Wo2^T + bo2
  f32x16 aO[2] = {zero16(), zero16()};
#pragma unroll
  for (int ks = 0; ks < 6; ++ks) {
    bf16x8 af = (ks < 4) ? xn[ks] : xan[ks - 4];
#pragma unroll
    for (int oh = 0; oh < 2; ++oh) aO[oh] = mm(af, LDW(Wo1, 96, oh, ks), aO[oh]);
  }
  const float bo1_[2] = {bo1[r31], bo1[32 + r31]};
  const float wo2_[2] = {Wo2[r31], Wo2[32 + r31]};
  const float bo2v = bo2[0];
#pragma unroll
  for (int reg = 0; reg < 16; ++reg) {
    float h0 = tanh_fast(aO[0][reg] + bo1_[0]);
    float h1 = tanh_fast(aO[1][reg] + bo1_[1]);
    float p = h0 * wo2_[0] + h1 * wo2_[1];
#pragma unroll
    for (int mks = 16; mks >= 1; mks >>= 1) p += __shfl_xor(p, mks, 64);
    if (r31 == 0) {
      int row = (reg & 3) + 8 * (reg >> 2) + 4 * h;
      out[R0 + row] = p + bo2v;
    }
  }
#undef LDW
}

extern "C" void kernel_launch(void* const* d_in, const int* in_sizes, int n_in,
                              void* d_out, int out_size, void* d_ws, size_t ws_size,
                              hipStream_t stream) {
  const float* prop  = (const float*)d_in[0];
  const float* annot = (const float*)d_in[1];
  const float* A     = (const float*)d_in[2];
  const float* Win   = (const float*)d_in[3];
  const float* bin   = (const float*)d_in[4];
  const float* Wr    = (const float*)d_in[5];
  const float* br    = (const float*)d_in[6];
  const float* Wz    = (const float*)d_in[7];
  const float* bz    = (const float*)d_in[8];
  const float* Wh    = (const float*)d_in[9];
  const float* bh    = (const float*)d_in[10];
  const float* Wo1   = (const float*)d_in[11];
  const float* bo1   = (const float*)d_in[12];
  const float* Wo2   = (const float*)d_in[13];
  const float* bo2   = (const float*)d_in[14];
  float* out = (float*)d_out;

  __bf16* Bt  = (__bf16*)d_ws;                                   // [B][64][16384] bf16 = 4 MB
  float*  a_in = (float*)((char*)d_ws + (size_t)Bz * Dd * Mm * sizeof(__bf16));  // [B][N][64] f32 = 2 MB

  k_build_bt<<<dim3(Nn / 64, Ee, Bz), 256, 0, stream>>>(prop, Win, bin, Bt);
  k_big_gemm<<<dim3(Bz * (Nn / 32)), 512, 0, stream>>>(A, Bt, a_in);
  k_gru<<<dim3(Bz * Nn / 32), 64, 0, stream>>>(a_in, prop, annot,
                                               Wr, br, Wz, bz, Wh, bh,
                                               Wo1, bo1, Wo2, bo2, out);
}